// Round 11
// baseline (311.914 us; speedup 1.0000x reference)
//
#include <hip/hip_runtime.h>
#include <type_traits>

// ---------------------------------------------------------------------------
// MultiHeadAttention fused pipeline for MI355X (gfx950)
// x[B,S,E] @ w_qkv -> split QKV -> RoPE -> causal GQA flash attention -> @ w_dense
// B=2 S=2048 E=2048 H=16 KVH=4 D=128
// R19 == R18 (previous round's bench failed on GPU acquisition; no data).
// R18: dense GEMM split-K=2. Evidence: 2-barrier GEMM TF ~ blocks/CU at the
//      BN=128 ratio (QKV 3/CU=853 TF vs dense 2/CU=569; BN=64's 4/CU only 610
//      because 16-MFMA/K-step ratio). Split-K gives BN=128's 32-MFMA ratio AND
//      4 blocks/CU: grid 16x32x2=1024, each block does K/2, fp32 atomicAdd
//      into memset-zeroed out (2-way IEEE add is commutative -> deterministic).
//      hipMemsetAsync is graph-capture-safe (harness reset uses it).
// R16: merged prep (neutral, kept); launch-gap theory falsified.
// R13: rope table (bit-identical trig) + 128B-contiguous V stores.
// R12: rope fused into QKV epilogue (table-driven since R13).
// R10: attn register-resident P via kv-permuted VT (see attn comment).
// ---------------------------------------------------------------------------

typedef __attribute__((ext_vector_type(8))) short short8;
typedef __attribute__((ext_vector_type(4))) float floatx4;
typedef __attribute__((ext_vector_type(4))) unsigned short ushort4v;
typedef __attribute__((ext_vector_type(4))) unsigned int uint4v;

constexpr int NH    = 16;
constexpr int NKV   = 4;
constexpr int HD    = 128;
constexpr int SEQ   = 2048;
constexpr int EMB   = 2048;
constexpr int NBATCH = 2;
constexpr int MROWS = NBATCH * SEQ;          // 4096
constexpr int NQKV  = (NH + 2 * NKV) * HD;   // 3072

__device__ __forceinline__ unsigned short f2b(float f) {
  union { float f; unsigned u; } v; v.f = f;
  unsigned u = v.u + 0x7FFFu + ((v.u >> 16) & 1u);   // RNE
  return (unsigned short)(u >> 16);
}
__device__ __forceinline__ float b2f(unsigned short h) {
  union { unsigned u; float f; } v; v.u = (unsigned)h << 16;
  return v.f;
}

// async global->LDS DMA, 16B per lane; lds dest = uniform base + lane*16
__device__ __forceinline__ void gload_lds16(const unsigned short* g,
                                            unsigned short* lds) {
  __builtin_amdgcn_global_load_lds(
      (const __attribute__((address_space(1))) unsigned int*)g,
      (__attribute__((address_space(3))) unsigned int*)lds, 16, 0, 0);
}

// ------------- merged prep: cvt x + weight transposes + rope table ----------
// blocks [0,8192): x fp32 -> bf16 (4 elems/thread, 16B loads / 8B stores)
// blocks [8192,14336): wqkv [2048][3072] -> bf16 [3072][2048]
// blocks [14336,18432): wdense [2048][2048] -> bf16 [2048][2048]^T
// blocks [18432,18944): rope (cos,sin) table [SEQ][64][2] f32
constexpr int PREP_CVT   = 8192;
constexpr int PREP_TQKV  = PREP_CVT + 6144;    // 96 x 64 tiles
constexpr int PREP_TD    = PREP_TQKV + 4096;   // 64 x 64 tiles
constexpr int PREP_TOTAL = PREP_TD + 512;

__global__ __launch_bounds__(256) void prep(
    const float* __restrict__ x, unsigned short* __restrict__ xb,
    const float* __restrict__ wqkv, unsigned short* __restrict__ oqkv,
    const float* __restrict__ wd, unsigned short* __restrict__ od,
    float* __restrict__ rtab) {
  const int blk = blockIdx.x;
  const int tid = threadIdx.x;
  __shared__ float t[32][33];
  if (blk < PREP_CVT) {
    const int i = (blk * 256 + tid) * 4;
    floatx4 v = *(const floatx4*)(x + i);
    ushort4v o = { f2b(v[0]), f2b(v[1]), f2b(v[2]), f2b(v[3]) };
    *(ushort4v*)(xb + i) = o;
  } else if (blk < PREP_TD) {
    const float* in;
    unsigned short* out;
    int C, cx, ry;
    if (blk < PREP_TQKV) {
      const int local = blk - PREP_CVT;
      in = wqkv; out = oqkv; C = NQKV; cx = local % 96; ry = local / 96;
    } else {
      const int local = blk - PREP_TQKV;
      in = wd; out = od; C = EMB; cx = local % 64; ry = local / 64;
    }
    const int c0 = cx * 32, r0 = ry * 32;
    const int tx = tid & 31, ty = tid >> 5;   // ty 0..7
#pragma unroll
    for (int i = 0; i < 32; i += 8)
      t[ty + i][tx] = in[(long)(r0 + ty + i) * C + (c0 + tx)];
    __syncthreads();
#pragma unroll
    for (int i = 0; i < 32; i += 8)
      out[(long)(c0 + ty + i) * EMB + (r0 + tx)] = f2b(t[tx][ty + i]);
  } else {
    const int idx = (blk - PREP_TD) * 256 + tid;   // 0..SEQ*64-1
    const int j = idx & 63, s = idx >> 6;
    const float e = -(float)j * (2.0f * 13.287712379549449f / 128.0f);
    const float ang = (float)s * exp2f(e);
    float sn, c;
    sincosf(ang, &sn, &c);
    rtab[idx * 2]     = c;
    rtab[idx * 2 + 1] = sn;
  }
}

// ------------------------------- GEMM (B^T) ---------------------------------
// C[M][N] = A[M][K](bf16) * BT[N][K](bf16)^T.  BM=128, BN=128, 4 waves.
// Unpadded LDS with XOR-swizzled 16B blocks (conflict-free fragment reads),
// global_load_lds width-16 staging. 32 MFMA per K-step per wave.
// MODE 0: full K, 3 blocks/CU (768 blocks). Q/K tiles -> LDS repack +
//         table-driven RoPE, 16B head-major stores; V -> 128B permuted stores.
// MODE 1: split-K via blockIdx.z (K/2 each), 4 blocks/CU (1024 blocks),
//         fp32 atomicAdd epilogue into memset-zeroed outF.
constexpr int BM = 128, BN = 128, BK = 64;

template <int MODE>
__global__ __launch_bounds__(256, MODE == 1 ? 4 : 3) void gemm_bt(
    const unsigned short* __restrict__ A,
    const unsigned short* __restrict__ BT,
    int Mdim, int Ndim, int Kdim,
    float* __restrict__ outF,
    unsigned short* __restrict__ Qb,
    unsigned short* __restrict__ Kb,
    unsigned short* __restrict__ Vt,
    const float* __restrict__ ropetab,
    float qscale) {
  __shared__ __align__(16) unsigned short smem[BM * BK + BN * BK];  // 32 KB
  unsigned short (*As)[BK] = (unsigned short (*)[BK])smem;
  unsigned short (*Bs)[BK] = (unsigned short (*)[BK])(smem + BM * BK);
  const int tid = threadIdx.x;
  const int bm = blockIdx.y * BM;
  const int bn = blockIdx.x * BN;
  const int wave = tid >> 6, lane = tid & 63;
  const int l = lane & 15, q = lane >> 4;
  const int l7 = l & 7;
  const int wm = (wave >> 1) * 64, wn = (wave & 1) * 64;

  floatx4 acc[4][4] = {};

  // DMA staging: one issue = 64 lanes x 16B = 1KB = 8 rows of 64 shorts.
  // Lane (srow=lane>>3, bp=lane&7) lands at phys block bp of row srow;
  // it FETCHES logical block bp^srow, so logical bl sits at phys bl^(row&7).
  const int srow = lane >> 3;                    // 0..7
  const int scol = ((lane & 7) ^ srow) * 8;      // swizzled source col (shorts)
  const unsigned short* Arow = A + (long)bm * Kdim;
  const unsigned short* Brow = BT + (long)bn * Kdim;

  // MODE 1: this block covers K-half blockIdx.z.
  const int kbeg = (MODE == 1) ? (int)blockIdx.z * (Kdim >> 1) : 0;
  const int kend = (MODE == 1) ? kbeg + (Kdim >> 1) : Kdim;

  for (int k0 = kbeg; k0 < kend; k0 += BK) {
#pragma unroll
    for (int i = 0; i < 4; ++i) {
      const int r0 = wave * 32 + i * 8;
      gload_lds16(Arow + (long)(r0 + srow) * Kdim + k0 + scol, &As[r0][0]);
      gload_lds16(Brow + (long)(r0 + srow) * Kdim + k0 + scol, &Bs[r0][0]);
    }
    __syncthreads();
#pragma unroll
    for (int kk = 0; kk < 2; ++kk) {
      short8 af[4], bfr[4];
#pragma unroll
      for (int mi = 0; mi < 4; ++mi)
        af[mi] = *(const short8*)&As[wm + mi * 16 + l][((kk * 4 + q) ^ l7) * 8];
#pragma unroll
      for (int ni = 0; ni < 4; ++ni)
        bfr[ni] = *(const short8*)&Bs[wn + ni * 16 + l][((kk * 4 + q) ^ l7) * 8];
#pragma unroll
      for (int mi = 0; mi < 4; ++mi)
#pragma unroll
        for (int ni = 0; ni < 4; ++ni)
          acc[mi][ni] = __builtin_amdgcn_mfma_f32_16x16x32_bf16(
              af[mi], bfr[ni], acc[mi][ni], 0, 0, 0);
    }
    __syncthreads();
  }

  if constexpr (MODE == 1) {
    // ---- split-K partial: fp32 atomicAdd (2-way commutative -> determin.) ----
#pragma unroll
    for (int mi = 0; mi < 4; ++mi) {
      const int rowbase = bm + wm + mi * 16 + q * 4;
#pragma unroll
      for (int ni = 0; ni < 4; ++ni) {
        const int col = bn + wn + ni * 16 + l;
#pragma unroll
        for (int r = 0; r < 4; ++r)
          atomicAdd(&outF[(long)(rowbase + r) * Ndim + col], acc[mi][ni][r]);
      }
    }
    return;
  }

  // ---- MODE 0 epilogues: all repack through swizzled Ct[128][128] ----
  // 16B-block col swizzle: blk_phys = (blk & 8) | ((blk ^ row) & 7).
  unsigned short (*Ct)[128] = (unsigned short (*)[128])smem;
#pragma unroll
  for (int mi = 0; mi < 4; ++mi)
#pragma unroll
    for (int ni = 0; ni < 4; ++ni)
#pragma unroll
      for (int r = 0; r < 4; ++r) {
        const int row = wm + mi * 16 + q * 4 + r;
        const int col = wn + ni * 16 + l;
        const int cs = ((((col >> 3) ^ row) & 7) | (col & 64 ? 8 : 0)) * 8 + (col & 7);
        Ct[row][cs] = f2b(acc[mi][ni][r]);
      }
  __syncthreads();

  if (bn >= (NH + NKV) * HD) {
    // ---- V tile: 128B contiguous permuted stores into VT[d][s] ----
    // attn needs VT[d][(s&~63)|p6] where p6 bits [5]=c2 [4:3]=qq [2]=u [1:0]=r
    // of s6 bits [5]=c2 [4]=u [3:2]=qq [1:0]=r. Gather with the inverse:
    // s6 = (p6&32) | ((p6&24)>>1) | ((p6&4)<<2) | (p6&3).
    const int hh = (bn - (NH + NKV) * HD) >> 7;
    const int d = tid >> 1, ch = tid & 1;        // d 0..127, s-chunk half
    const int m0 = bm + ch * 64;
    const int bb = m0 >> 11, sbase = m0 & (SEQ - 1);
    unsigned short* vrow =
        Vt + ((long)(bb * NKV + hh)) * HD * SEQ + (long)d * SEQ + sbase;
    const int dblk = d >> 3, dlo = d & 7, dhi = (d & 64) ? 8 : 0;
#pragma unroll
    for (int pb = 0; pb < 8; ++pb) {             // 8 x 16B stores = 128B
      short8 ov;
#pragma unroll
      for (int j = 0; j < 8; ++j) {
        const int p6 = pb * 8 + j;
        const int s6 = (p6 & 32) | ((p6 & 24) >> 1) | ((p6 & 4) << 2) | (p6 & 3);
        const int row = ch * 64 + s6;
        const int cs = (((dblk ^ row) & 7) | dhi) * 8 + dlo;
        ov[j] = (short)Ct[row][cs];
      }
      *(short8*)(vrow + pb * 8) = ov;
    }
  } else {
    // ---- Q/K tiles: table-driven RoPE + 16B head-major stores ----
    const int row = tid >> 1, g = tid & 1;
    const int m = bm + row, bb = m >> 11, s = m & (SEQ - 1);
    const bool isQ = (bn < NH * HD);
    unsigned short* dst;
    if (isQ) dst = Qb + (((long)(bb * NH + (bn >> 7))) * SEQ + s) * HD;
    else     dst = Kb + (((long)(bb * NKV + ((bn - NH * HD) >> 7))) * SEQ + s) * HD;
    const float scale = isQ ? qscale : 1.0f;
    const float* trow = ropetab + (long)s * 128;   // 64 (cos,sin) pairs
#pragma unroll
    for (int i = 0; i < 8; ++i) {
      const int lbo = g * 8 + i;                  // own logical 16B block
      const int lbx = (g ^ 1) * 8 + i;            // other-half logical block
      const int pbo = (lbo & 8) | ((lbo ^ row) & 7);
      const int pbx = (lbx & 8) | ((lbx ^ row) & 7);
      short8 xo = *(const short8*)&Ct[row][pbo * 8];
      short8 xx = *(const short8*)&Ct[row][pbx * 8];
      floatx4 t0 = *(const floatx4*)(trow + i * 16);
      floatx4 t1 = *(const floatx4*)(trow + i * 16 + 4);
      floatx4 t2 = *(const floatx4*)(trow + i * 16 + 8);
      floatx4 t3 = *(const floatx4*)(trow + i * 16 + 12);
      const float cc[8] = { t0[0], t0[2], t1[0], t1[2], t2[0], t2[2], t3[0], t3[2] };
      const float ss[8] = { t0[1], t0[3], t1[1], t1[3], t2[1], t2[3], t3[1], t3[3] };
      short8 outv;
#pragma unroll
      for (int j2 = 0; j2 < 8; ++j2) {
        const float xown = b2f((unsigned short)xo[j2]);
        const float xoth = b2f((unsigned short)xx[j2]);
        const float rr = g ? (xown * cc[j2] + xoth * ss[j2])
                           : (xown * cc[j2] - xoth * ss[j2]);
        outv[j2] = (short)f2b(rr * scale);
      }
      *(short8*)(dst + g * 64 + i * 8) = outv;
    }
  }
}

// --------------------------- flash attention --------------------------------
// R10 structure: 128-row q-tiles, 4 waves x 32 q-rows (2 mh sub-tiles of 16).
// Swapped QK^T (sf = mfma(K,Q)) -> lane holds P[kv=ni*16+q*4+r][qrow=l].
// P stays in registers: cvt_pk pairs -> 4 u32 = short8 = PV A-fragment under
// the kv-permutation baked into VT's global layout (see gemm V-epilogue).
// LDS: Ks 32K + VTs 32K = 64KB -> 2 blocks/CU.
// Grid (16,16,2); t = b ? 15-bx : bx so the two co-resident blocks per CU
// (linear ids i, i+256) carry complementary tiles -> uniform 34 chunks/CU.
__global__ __launch_bounds__(256, 2) void attn_kernel(
    const unsigned short* __restrict__ Q,   // [B][NH][S][D], pre-scaled by 1/sqrt(d)*log2e
    const unsigned short* __restrict__ K,   // [B][NKV][S][D]
    const unsigned short* __restrict__ VT,  // [B][NKV][D][S], kv-permuted per 64
    unsigned short* __restrict__ attn) {    // [B*S][NH*D]
  const int h = blockIdx.y, b = blockIdx.z;
  const int t = b ? (15 - (int)blockIdx.x) : (int)blockIdx.x;  // q-tile (128 rows)
  const int kvh = h >> 2;   // jnp.repeat: q head h uses kv head h/4
  const int tid = threadIdx.x;
  const int wave = tid >> 6, lane = tid & 63;
  const int l = lane & 15, q = lane >> 4;
  const int l7 = l & 7;
  const int wq = wave * 32;

  const unsigned short* Kh  = K  + ((long)(b * NKV + kvh)) * SEQ * HD;
  const unsigned short* VTh = VT + ((long)(b * NKV + kvh)) * HD * SEQ;

  __shared__ __align__(16) unsigned short smem[2 * 64 * 128 + 2 * 128 * 64]; // 64 KB
  unsigned short (*Ks)[64 * 128]  = (unsigned short (*)[64 * 128])smem;
  unsigned short (*VTs)[128 * 64] = (unsigned short (*)[128 * 64])(smem + 2 * 64 * 128);

  int koff[4], voff[4];
  {
    const int k_rl = lane >> 4, k_bp = lane & 15;
    const int v_rl = lane >> 3, v_bp = lane & 7;
#pragma unroll
    for (int j = 0; j < 4; ++j) {
      const int rk = (wave * 4 + j) * 4 + k_rl;
      koff[j] = rk * HD + (k_bp ^ (rk & 15)) * 8;
      const int rv = (wave * 4 + j) * 8 + v_rl;
      voff[j] = rv * SEQ + (v_bp ^ (rv & 7)) * 8;
    }
  }

  short8 onesf;
#pragma unroll
  for (int i = 0; i < 8; ++i) onesf[i] = (short)0x3F80;   // bf16 1.0

  auto stage = [&](int c, int buf) {
    const unsigned short* kc = Kh + c * (64 * HD);
    const unsigned short* vc = VTh + c * 64;
#pragma unroll
    for (int j = 0; j < 4; ++j)
      gload_lds16(kc + koff[j], &Ks[buf][(wave * 4 + j) * 4 * 128]);
#pragma unroll
    for (int j = 0; j < 4; ++j)
      gload_lds16(vc + voff[j], &VTs[buf][(wave * 4 + j) * 8 * 64]);
  };

  const unsigned short* Qh = Q + (((long)(b * NH + h)) * SEQ + t * 128) * HD;
  short8 qf[2][4];
#pragma unroll
  for (int mh = 0; mh < 2; ++mh)
#pragma unroll
    for (int kk = 0; kk < 4; ++kk)
      qf[mh][kk] = *(const short8*)(Qh + (long)(wq + mh * 16 + l) * HD + kk * 32 + q * 8);

  floatx4 o[2][9] = {};   // [mh][0..7]=O d-tiles, [8]=denominator (ones col)

  auto chunk_body = [&](auto masked, int cur, int kv0) {
    constexpr bool MASKED = decltype(masked)::value;
    floatx4 sf[2][4] = {};
#pragma unroll
    for (int kk = 0; kk < 4; ++kk) {
      short8 kf[4];
#pragma unroll
      for (int ni = 0; ni < 4; ++ni)
        kf[ni] = *(const short8*)&Ks[cur][(ni * 16 + l) * 128 + (((kk * 4 + q) ^ l) * 8)];
#pragma unroll
      for (int mh = 0; mh < 2; ++mh)
#pragma unroll
        for (int ni = 0; ni < 4; ++ni)
          sf[mh][ni] = __builtin_amdgcn_mfma_f32_16x16x32_bf16(
              kf[ni], qf[mh][kk], sf[mh][ni], 0, 0, 0);
    }
    short8 pf[2][2];
#pragma unroll
    for (int mh = 0; mh < 2; ++mh) {
      const int qrow = t * 128 + wq + mh * 16 + l;
      unsigned u[8];
#pragma unroll
      for (int ni = 0; ni < 4; ++ni) {
        if constexpr (MASKED) {
#pragma unroll
          for (int r = 0; r < 4; ++r)
            if (kv0 + ni * 16 + q * 4 + r > qrow) sf[mh][ni][r] = -3e38f;  // exp2 -> 0
        }
        float e0 = exp2f(sf[mh][ni][0]);
        float e1 = exp2f(sf[mh][ni][1]);
        float e2 = exp2f(sf[mh][ni][2]);
        float e3 = exp2f(sf[mh][ni][3]);
        asm("v_cvt_pk_bf16_f32 %0, %1, %2" : "=v"(u[ni * 2]) : "v"(e0), "v"(e1));
        asm("v_cvt_pk_bf16_f32 %0, %1, %2" : "=v"(u[ni * 2 + 1]) : "v"(e2), "v"(e3));
      }
      union { uint4v v; short8 s; } a0, a1;
      a0.v = (uint4v){u[0], u[1], u[2], u[3]};
      a1.v = (uint4v){u[4], u[5], u[6], u[7]};
      pf[mh][0] = a0.s;   // kv-slots: pi(8q+j) = q*4+(j&3) + (j>=4)*16
      pf[mh][1] = a1.s;   // + 32
    }
#pragma unroll
    for (int c2 = 0; c2 < 2; ++c2) {
      const int pb = ((c2 * 4 + q) ^ l7) * 8;
#pragma unroll
      for (int di = 0; di < 8; ++di) {
        short8 vf = *(const short8*)&VTs[cur][(di * 16 + l) * 64 + pb];
        o[0][di] = __builtin_amdgcn_mfma_f32_16x16x32_bf16(pf[0][c2], vf, o[0][di], 0, 0, 0);
        o[1][di] = __builtin_amdgcn_mfma_f32_16x16x32_bf16(pf[1][c2], vf, o[1][di], 0, 0, 0);
      }
      o[0][8] = __builtin_amdgcn_mfma_f32_16x16x32_bf16(pf[0][c2], onesf, o[0][8], 0, 0, 0);
      o[1][8] = __builtin_amdgcn_mfma_f32_16x16x32_bf16(pf[1][c2], onesf, o[1][8], 0, 0, 0);
    }
  };

  const int nc = 2 * t + 2;   // causal: kv up to 128t+127, Tk=64
  stage(0, 0);
  __syncthreads();

  int c = 0;
#pragma unroll 1
  for (; c < nc - 2; ++c) {
    stage(c + 1, (c & 1) ^ 1);
    chunk_body(std::false_type{}, c & 1, c * 64);
    __syncthreads();   // prefetch DMA drained; all reads of cur done
  }
  stage(c + 1, (c & 1) ^ 1);
  chunk_body(std::true_type{}, c & 1, c * 64);
  __syncthreads();
  ++c;
  chunk_body(std::true_type{}, c & 1, c * 64);
  __syncthreads();     // all waves done reading Ks/VTs before repack overwrite

  unsigned short (*Ob)[136] = (unsigned short (*)[136])smem;  // 34.8 KB < 64 KB
#pragma unroll
  for (int mh = 0; mh < 2; ++mh)
#pragma unroll
    for (int r = 0; r < 4; ++r) {
      const float inv = 1.0f / o[mh][8][r];   // l (same value in every lane)
#pragma unroll
      for (int di = 0; di < 8; ++di)
        Ob[wq + mh * 16 + q * 4 + r][di * 16 + l] = f2b(o[mh][di][r] * inv);
    }
  __syncthreads();
  {
    const int row = tid >> 1, g = (tid & 1) * 64;
    const int s = t * 128 + row;
    unsigned short* dst = attn + ((long)(b * SEQ + s)) * (NH * HD) + h * HD + g;
#pragma unroll
    for (int j = 0; j < 8; ++j)
      *(short8*)(dst + j * 8) = *(const short8*)&Ob[row][g + j * 8];
  }
}

// ---------------------------------------------------------------------------
extern "C" void kernel_launch(void* const* d_in, const int* in_sizes, int n_in,
                              void* d_out, int out_size, void* d_ws, size_t ws_size,
                              hipStream_t stream) {
  const float* x       = (const float*)d_in[0];   // [2,2048,2048]
  const float* w_qkv   = (const float*)d_in[1];   // [2048,3072]
  const float* w_dense = (const float*)d_in[2];   // [2048,2048]
  float* out = (float*)d_out;                     // [2,2048,2048] fp32

  char* ws = (char*)d_ws;
  const size_t MB = 1024 * 1024;
  unsigned short* xb    = (unsigned short*)(ws);            // 16 MB (aliased as attn later)
  unsigned short* wqkvT = (unsigned short*)(ws + 16 * MB);  // 12 MB
  unsigned short* wdT   = (unsigned short*)(ws + 28 * MB);  //  8 MB
  unsigned short* Qb    = (unsigned short*)(ws + 36 * MB);  // 16 MB
  unsigned short* Kb    = (unsigned short*)(ws + 52 * MB);  //  4 MB
  unsigned short* VTb   = (unsigned short*)(ws + 56 * MB);  //  4 MB
  float*          rtab  = (float*)(ws + 60 * MB);           //  1 MB  (total 61 MB)
  unsigned short* attn  = xb;   // x no longer needed after qkv GEMM

  const float qscale = 0.08838834764831845f * 1.4426950408889634f; // 1/sqrt(128)*log2e

  // zero out for split-K atomic accumulation (graph-capture-safe)
  hipMemsetAsync(out, 0, (size_t)out_size, stream);

  prep<<<PREP_TOTAL, 256, 0, stream>>>(x, xb, w_qkv, wqkvT, w_dense, wdT, rtab);

  // QKV GEMM with fused table-RoPE in the Q/K epilogue (BN=128, 768 blocks, 3/CU)
  gemm_bt<0><<<dim3(NQKV / BN, MROWS / BM), 256, 0, stream>>>(
      xb, wqkvT, MROWS, NQKV, EMB, nullptr, Qb, Kb, VTb, rtab, qscale);

  attn_kernel<<<dim3(16, NH, NBATCH), 256, 0, stream>>>(Qb, Kb, VTb, attn);

  // dense GEMM: split-K=2 (1024 blocks, 4/CU), fp32 atomicAdd epilogue
  gemm_bt<1><<<dim3(EMB / BN, MROWS / BM, 2), 256, 0, stream>>>(
      attn, wdT, MROWS, EMB, NH * HD, out, nullptr, nullptr, nullptr, nullptr, 0.0f);
}

// Round 12
// 262.828 us; speedup vs baseline: 1.1868x; 1.1868x over previous
//
#include <hip/hip_runtime.h>
#include <type_traits>

// ---------------------------------------------------------------------------
// MultiHeadAttention fused pipeline for MI355X (gfx950)
// x[B,S,E] @ w_qkv -> split QKV -> RoPE -> causal GQA flash attention -> @ w_dense
// B=2 S=2048 E=2048 H=16 KVH=4 D=128
// R20: revert R18/R19 split-K (dense 55->79us: 16.8M fp32 atomicAdds serialize
//      through L2 -- VALUBusy 9%, MfmaUtil 17%; epilogue cost term ignored by
//      the blocks/CU model). Back to best-known config (R13=275.3 / R16=276.2,
//      statistically tied): merged prep, BN=128 QKV + table-RoPE epilogue,
//      BN=64 dense (1024 blocks, 4/CU), R10 attn.
// R16: merged prep (neutral, kept); launch-gap theory falsified.
// R13: rope table (bit-identical trig) + 128B-contiguous V stores.
// R12: dense GEMM BN=64; rope fused into QKV epilogue (table-driven since R13).
// R10: attn register-resident P via kv-permuted VT (see attn comment).
// ---------------------------------------------------------------------------

typedef __attribute__((ext_vector_type(8))) short short8;
typedef __attribute__((ext_vector_type(4))) float floatx4;
typedef __attribute__((ext_vector_type(4))) unsigned short ushort4v;
typedef __attribute__((ext_vector_type(4))) unsigned int uint4v;

constexpr int NH    = 16;
constexpr int NKV   = 4;
constexpr int HD    = 128;
constexpr int SEQ   = 2048;
constexpr int EMB   = 2048;
constexpr int NBATCH = 2;
constexpr int MROWS = NBATCH * SEQ;          // 4096
constexpr int NQKV  = (NH + 2 * NKV) * HD;   // 3072

__device__ __forceinline__ unsigned short f2b(float f) {
  union { float f; unsigned u; } v; v.f = f;
  unsigned u = v.u + 0x7FFFu + ((v.u >> 16) & 1u);   // RNE
  return (unsigned short)(u >> 16);
}
__device__ __forceinline__ float b2f(unsigned short h) {
  union { unsigned u; float f; } v; v.u = (unsigned)h << 16;
  return v.f;
}

// async global->LDS DMA, 16B per lane; lds dest = uniform base + lane*16
__device__ __forceinline__ void gload_lds16(const unsigned short* g,
                                            unsigned short* lds) {
  __builtin_amdgcn_global_load_lds(
      (const __attribute__((address_space(1))) unsigned int*)g,
      (__attribute__((address_space(3))) unsigned int*)lds, 16, 0, 0);
}

// ------------- merged prep: cvt x + weight transposes + rope table ----------
// blocks [0,8192): x fp32 -> bf16 (4 elems/thread, 16B loads / 8B stores)
// blocks [8192,14336): wqkv [2048][3072] -> bf16 [3072][2048]
// blocks [14336,18432): wdense [2048][2048] -> bf16 [2048][2048]^T
// blocks [18432,18944): rope (cos,sin) table [SEQ][64][2] f32
constexpr int PREP_CVT   = 8192;
constexpr int PREP_TQKV  = PREP_CVT + 6144;    // 96 x 64 tiles
constexpr int PREP_TD    = PREP_TQKV + 4096;   // 64 x 64 tiles
constexpr int PREP_TOTAL = PREP_TD + 512;

__global__ __launch_bounds__(256) void prep(
    const float* __restrict__ x, unsigned short* __restrict__ xb,
    const float* __restrict__ wqkv, unsigned short* __restrict__ oqkv,
    const float* __restrict__ wd, unsigned short* __restrict__ od,
    float* __restrict__ rtab) {
  const int blk = blockIdx.x;
  const int tid = threadIdx.x;
  __shared__ float t[32][33];
  if (blk < PREP_CVT) {
    const int i = (blk * 256 + tid) * 4;
    floatx4 v = *(const floatx4*)(x + i);
    ushort4v o = { f2b(v[0]), f2b(v[1]), f2b(v[2]), f2b(v[3]) };
    *(ushort4v*)(xb + i) = o;
  } else if (blk < PREP_TD) {
    const float* in;
    unsigned short* out;
    int C, cx, ry;
    if (blk < PREP_TQKV) {
      const int local = blk - PREP_CVT;
      in = wqkv; out = oqkv; C = NQKV; cx = local % 96; ry = local / 96;
    } else {
      const int local = blk - PREP_TQKV;
      in = wd; out = od; C = EMB; cx = local % 64; ry = local / 64;
    }
    const int c0 = cx * 32, r0 = ry * 32;
    const int tx = tid & 31, ty = tid >> 5;   // ty 0..7
#pragma unroll
    for (int i = 0; i < 32; i += 8)
      t[ty + i][tx] = in[(long)(r0 + ty + i) * C + (c0 + tx)];
    __syncthreads();
#pragma unroll
    for (int i = 0; i < 32; i += 8)
      out[(long)(c0 + ty + i) * EMB + (r0 + tx)] = f2b(t[tx][ty + i]);
  } else {
    const int idx = (blk - PREP_TD) * 256 + tid;   // 0..SEQ*64-1
    const int j = idx & 63, s = idx >> 6;
    const float e = -(float)j * (2.0f * 13.287712379549449f / 128.0f);
    const float ang = (float)s * exp2f(e);
    float sn, c;
    sincosf(ang, &sn, &c);
    rtab[idx * 2]     = c;
    rtab[idx * 2 + 1] = sn;
  }
}

// ------------------------------- GEMM (B^T) ---------------------------------
// C[M][N] = A[M][K](bf16) * BT[N][K](bf16)^T.  BM=128 tile, 4 waves.
// Unpadded LDS with XOR-swizzled 16B blocks (conflict-free fragment reads),
// global_load_lds width-16 staging.
// MODE 0: BN=128, 3 blocks/CU. Q/K tiles -> LDS repack + table-driven RoPE,
//         16B head-major stores; V tiles -> LDS repack + 128B permuted stores.
// MODE 1: BN=64, 4 blocks/CU (1024 blocks). fp32 dense store to outF.
constexpr int BM = 128, BK = 64;

template <int MODE>
__global__ __launch_bounds__(256, MODE == 1 ? 4 : 3) void gemm_bt(
    const unsigned short* __restrict__ A,
    const unsigned short* __restrict__ BT,
    int Mdim, int Ndim, int Kdim,
    float* __restrict__ outF,
    unsigned short* __restrict__ Qb,
    unsigned short* __restrict__ Kb,
    unsigned short* __restrict__ Vt,
    const float* __restrict__ ropetab,
    float qscale) {
  constexpr int TBN = (MODE == 1) ? 64 : 128;     // tile N
  constexpr int NI  = TBN / 32;                   // 16-col frags per wave
  __shared__ __align__(16) unsigned short smem[BM * BK + TBN * BK];
  unsigned short (*As)[BK] = (unsigned short (*)[BK])smem;
  unsigned short (*Bs)[BK] = (unsigned short (*)[BK])(smem + BM * BK);
  const int tid = threadIdx.x;
  const int bm = blockIdx.y * BM;
  const int bn = blockIdx.x * TBN;
  const int wave = tid >> 6, lane = tid & 63;
  const int l = lane & 15, q = lane >> 4;
  const int l7 = l & 7;
  const int wm = (wave >> 1) * 64, wn = (wave & 1) * (TBN / 2);

  floatx4 acc[4][NI] = {};

  // DMA staging: one issue = 64 lanes x 16B = 1KB = 8 rows of 64 shorts.
  // Lane (srow=lane>>3, bp=lane&7) lands at phys block bp of row srow;
  // it FETCHES logical block bp^srow, so logical bl sits at phys bl^(row&7).
  const int srow = lane >> 3;                    // 0..7
  const int scol = ((lane & 7) ^ srow) * 8;      // swizzled source col (shorts)
  const unsigned short* Arow = A + (long)bm * Kdim;
  const unsigned short* Brow = BT + (long)bn * Kdim;

  for (int k0 = 0; k0 < Kdim; k0 += BK) {
#pragma unroll
    for (int i = 0; i < 4; ++i) {
      const int r0 = wave * 32 + i * 8;
      gload_lds16(Arow + (long)(r0 + srow) * Kdim + k0 + scol, &As[r0][0]);
    }
#pragma unroll
    for (int i = 0; i < TBN / 32; ++i) {
      const int r0 = wave * (TBN / 4) + i * 8;
      gload_lds16(Brow + (long)(r0 + srow) * Kdim + k0 + scol, &Bs[r0][0]);
    }
    __syncthreads();
#pragma unroll
    for (int kk = 0; kk < 2; ++kk) {
      short8 af[4], bfr[NI];
#pragma unroll
      for (int mi = 0; mi < 4; ++mi)
        af[mi] = *(const short8*)&As[wm + mi * 16 + l][((kk * 4 + q) ^ l7) * 8];
#pragma unroll
      for (int ni = 0; ni < NI; ++ni)
        bfr[ni] = *(const short8*)&Bs[wn + ni * 16 + l][((kk * 4 + q) ^ l7) * 8];
#pragma unroll
      for (int mi = 0; mi < 4; ++mi)
#pragma unroll
        for (int ni = 0; ni < NI; ++ni)
          acc[mi][ni] = __builtin_amdgcn_mfma_f32_16x16x32_bf16(
              af[mi], bfr[ni], acc[mi][ni], 0, 0, 0);
    }
    __syncthreads();
  }

  if constexpr (MODE == 1) {
#pragma unroll
    for (int mi = 0; mi < 4; ++mi) {
      const int rowbase = bm + wm + mi * 16 + q * 4;
#pragma unroll
      for (int ni = 0; ni < NI; ++ni) {
        const int col = bn + wn + ni * 16 + l;
#pragma unroll
        for (int r = 0; r < 4; ++r)
          outF[(long)(rowbase + r) * Ndim + col] = acc[mi][ni][r];
      }
    }
    return;
  }

  // ---- MODE 0 epilogues: all repack through swizzled Ct[128][128] ----
  // 16B-block col swizzle: blk_phys = (blk & 8) | ((blk ^ row) & 7).
  unsigned short (*Ct)[128] = (unsigned short (*)[128])smem;
#pragma unroll
  for (int mi = 0; mi < 4; ++mi)
#pragma unroll
    for (int ni = 0; ni < NI; ++ni)
#pragma unroll
      for (int r = 0; r < 4; ++r) {
        const int row = wm + mi * 16 + q * 4 + r;
        const int col = wn + ni * 16 + l;
        const int cs = ((((col >> 3) ^ row) & 7) | (col & 64 ? 8 : 0)) * 8 + (col & 7);
        Ct[row][cs] = f2b(acc[mi][ni][r]);
      }
  __syncthreads();

  if (bn >= (NH + NKV) * HD) {
    // ---- V tile: 128B contiguous permuted stores into VT[d][s] ----
    // attn needs VT[d][(s&~63)|p6] where p6 bits [5]=c2 [4:3]=qq [2]=u [1:0]=r
    // of s6 bits [5]=c2 [4]=u [3:2]=qq [1:0]=r. Gather with the inverse:
    // s6 = (p6&32) | ((p6&24)>>1) | ((p6&4)<<2) | (p6&3).
    const int hh = (bn - (NH + NKV) * HD) >> 7;
    const int d = tid >> 1, ch = tid & 1;        // d 0..127, s-chunk half
    const int m0 = bm + ch * 64;
    const int bb = m0 >> 11, sbase = m0 & (SEQ - 1);
    unsigned short* vrow =
        Vt + ((long)(bb * NKV + hh)) * HD * SEQ + (long)d * SEQ + sbase;
    const int dblk = d >> 3, dlo = d & 7, dhi = (d & 64) ? 8 : 0;
#pragma unroll
    for (int pb = 0; pb < 8; ++pb) {             // 8 x 16B stores = 128B
      short8 ov;
#pragma unroll
      for (int j = 0; j < 8; ++j) {
        const int p6 = pb * 8 + j;
        const int s6 = (p6 & 32) | ((p6 & 24) >> 1) | ((p6 & 4) << 2) | (p6 & 3);
        const int row = ch * 64 + s6;
        const int cs = (((dblk ^ row) & 7) | dhi) * 8 + dlo;
        ov[j] = (short)Ct[row][cs];
      }
      *(short8*)(vrow + pb * 8) = ov;
    }
  } else {
    // ---- Q/K tiles: table-driven RoPE + 16B head-major stores ----
    const int row = tid >> 1, g = tid & 1;
    const int m = bm + row, bb = m >> 11, s = m & (SEQ - 1);
    const bool isQ = (bn < NH * HD);
    unsigned short* dst;
    if (isQ) dst = Qb + (((long)(bb * NH + (bn >> 7))) * SEQ + s) * HD;
    else     dst = Kb + (((long)(bb * NKV + ((bn - NH * HD) >> 7))) * SEQ + s) * HD;
    const float scale = isQ ? qscale : 1.0f;
    const float* trow = ropetab + (long)s * 128;   // 64 (cos,sin) pairs
#pragma unroll
    for (int i = 0; i < 8; ++i) {
      const int lbo = g * 8 + i;                  // own logical 16B block
      const int lbx = (g ^ 1) * 8 + i;            // other-half logical block
      const int pbo = (lbo & 8) | ((lbo ^ row) & 7);
      const int pbx = (lbx & 8) | ((lbx ^ row) & 7);
      short8 xo = *(const short8*)&Ct[row][pbo * 8];
      short8 xx = *(const short8*)&Ct[row][pbx * 8];
      floatx4 t0 = *(const floatx4*)(trow + i * 16);
      floatx4 t1 = *(const floatx4*)(trow + i * 16 + 4);
      floatx4 t2 = *(const floatx4*)(trow + i * 16 + 8);
      floatx4 t3 = *(const floatx4*)(trow + i * 16 + 12);
      const float cc[8] = { t0[0], t0[2], t1[0], t1[2], t2[0], t2[2], t3[0], t3[2] };
      const float ss[8] = { t0[1], t0[3], t1[1], t1[3], t2[1], t2[3], t3[1], t3[3] };
      short8 outv;
#pragma unroll
      for (int j2 = 0; j2 < 8; ++j2) {
        const float xown = b2f((unsigned short)xo[j2]);
        const float xoth = b2f((unsigned short)xx[j2]);
        const float rr = g ? (xown * cc[j2] + xoth * ss[j2])
                           : (xown * cc[j2] - xoth * ss[j2]);
        outv[j2] = (short)f2b(rr * scale);
      }
      *(short8*)(dst + g * 64 + i * 8) = outv;
    }
  }
}

// --------------------------- flash attention --------------------------------
// R10 structure: 128-row q-tiles, 4 waves x 32 q-rows (2 mh sub-tiles of 16).
// Swapped QK^T (sf = mfma(K,Q)) -> lane holds P[kv=ni*16+q*4+r][qrow=l].
// P stays in registers: cvt_pk pairs -> 4 u32 = short8 = PV A-fragment under
// the kv-permutation baked into VT's global layout (see gemm V-epilogue).
// LDS: Ks 32K + VTs 32K = 64KB -> 2 blocks/CU.
// Grid (16,16,2); t = b ? 15-bx : bx so the two co-resident blocks per CU
// (linear ids i, i+256) carry complementary tiles -> uniform 34 chunks/CU.
__global__ __launch_bounds__(256, 2) void attn_kernel(
    const unsigned short* __restrict__ Q,   // [B][NH][S][D], pre-scaled by 1/sqrt(d)*log2e
    const unsigned short* __restrict__ K,   // [B][NKV][S][D]
    const unsigned short* __restrict__ VT,  // [B][NKV][D][S], kv-permuted per 64
    unsigned short* __restrict__ attn) {    // [B*S][NH*D]
  const int h = blockIdx.y, b = blockIdx.z;
  const int t = b ? (15 - (int)blockIdx.x) : (int)blockIdx.x;  // q-tile (128 rows)
  const int kvh = h >> 2;   // jnp.repeat: q head h uses kv head h/4
  const int tid = threadIdx.x;
  const int wave = tid >> 6, lane = tid & 63;
  const int l = lane & 15, q = lane >> 4;
  const int l7 = l & 7;
  const int wq = wave * 32;

  const unsigned short* Kh  = K  + ((long)(b * NKV + kvh)) * SEQ * HD;
  const unsigned short* VTh = VT + ((long)(b * NKV + kvh)) * HD * SEQ;

  __shared__ __align__(16) unsigned short smem[2 * 64 * 128 + 2 * 128 * 64]; // 64 KB
  unsigned short (*Ks)[64 * 128]  = (unsigned short (*)[64 * 128])smem;
  unsigned short (*VTs)[128 * 64] = (unsigned short (*)[128 * 64])(smem + 2 * 64 * 128);

  int koff[4], voff[4];
  {
    const int k_rl = lane >> 4, k_bp = lane & 15;
    const int v_rl = lane >> 3, v_bp = lane & 7;
#pragma unroll
    for (int j = 0; j < 4; ++j) {
      const int rk = (wave * 4 + j) * 4 + k_rl;
      koff[j] = rk * HD + (k_bp ^ (rk & 15)) * 8;
      const int rv = (wave * 4 + j) * 8 + v_rl;
      voff[j] = rv * SEQ + (v_bp ^ (rv & 7)) * 8;
    }
  }

  short8 onesf;
#pragma unroll
  for (int i = 0; i < 8; ++i) onesf[i] = (short)0x3F80;   // bf16 1.0

  auto stage = [&](int c, int buf) {
    const unsigned short* kc = Kh + c * (64 * HD);
    const unsigned short* vc = VTh + c * 64;
#pragma unroll
    for (int j = 0; j < 4; ++j)
      gload_lds16(kc + koff[j], &Ks[buf][(wave * 4 + j) * 4 * 128]);
#pragma unroll
    for (int j = 0; j < 4; ++j)
      gload_lds16(vc + voff[j], &VTs[buf][(wave * 4 + j) * 8 * 64]);
  };

  const unsigned short* Qh = Q + (((long)(b * NH + h)) * SEQ + t * 128) * HD;
  short8 qf[2][4];
#pragma unroll
  for (int mh = 0; mh < 2; ++mh)
#pragma unroll
    for (int kk = 0; kk < 4; ++kk)
      qf[mh][kk] = *(const short8*)(Qh + (long)(wq + mh * 16 + l) * HD + kk * 32 + q * 8);

  floatx4 o[2][9] = {};   // [mh][0..7]=O d-tiles, [8]=denominator (ones col)

  auto chunk_body = [&](auto masked, int cur, int kv0) {
    constexpr bool MASKED = decltype(masked)::value;
    floatx4 sf[2][4] = {};
#pragma unroll
    for (int kk = 0; kk < 4; ++kk) {
      short8 kf[4];
#pragma unroll
      for (int ni = 0; ni < 4; ++ni)
        kf[ni] = *(const short8*)&Ks[cur][(ni * 16 + l) * 128 + (((kk * 4 + q) ^ l) * 8)];
#pragma unroll
      for (int mh = 0; mh < 2; ++mh)
#pragma unroll
        for (int ni = 0; ni < 4; ++ni)
          sf[mh][ni] = __builtin_amdgcn_mfma_f32_16x16x32_bf16(
              kf[ni], qf[mh][kk], sf[mh][ni], 0, 0, 0);
    }
    short8 pf[2][2];
#pragma unroll
    for (int mh = 0; mh < 2; ++mh) {
      const int qrow = t * 128 + wq + mh * 16 + l;
      unsigned u[8];
#pragma unroll
      for (int ni = 0; ni < 4; ++ni) {
        if constexpr (MASKED) {
#pragma unroll
          for (int r = 0; r < 4; ++r)
            if (kv0 + ni * 16 + q * 4 + r > qrow) sf[mh][ni][r] = -3e38f;  // exp2 -> 0
        }
        float e0 = exp2f(sf[mh][ni][0]);
        float e1 = exp2f(sf[mh][ni][1]);
        float e2 = exp2f(sf[mh][ni][2]);
        float e3 = exp2f(sf[mh][ni][3]);
        asm("v_cvt_pk_bf16_f32 %0, %1, %2" : "=v"(u[ni * 2]) : "v"(e0), "v"(e1));
        asm("v_cvt_pk_bf16_f32 %0, %1, %2" : "=v"(u[ni * 2 + 1]) : "v"(e2), "v"(e3));
      }
      union { uint4v v; short8 s; } a0, a1;
      a0.v = (uint4v){u[0], u[1], u[2], u[3]};
      a1.v = (uint4v){u[4], u[5], u[6], u[7]};
      pf[mh][0] = a0.s;   // kv-slots: pi(8q+j) = q*4+(j&3) + (j>=4)*16
      pf[mh][1] = a1.s;   // + 32
    }
#pragma unroll
    for (int c2 = 0; c2 < 2; ++c2) {
      const int pb = ((c2 * 4 + q) ^ l7) * 8;
#pragma unroll
      for (int di = 0; di < 8; ++di) {
        short8 vf = *(const short8*)&VTs[cur][(di * 16 + l) * 64 + pb];
        o[0][di] = __builtin_amdgcn_mfma_f32_16x16x32_bf16(pf[0][c2], vf, o[0][di], 0, 0, 0);
        o[1][di] = __builtin_amdgcn_mfma_f32_16x16x32_bf16(pf[1][c2], vf, o[1][di], 0, 0, 0);
      }
      o[0][8] = __builtin_amdgcn_mfma_f32_16x16x32_bf16(pf[0][c2], onesf, o[0][8], 0, 0, 0);
      o[1][8] = __builtin_amdgcn_mfma_f32_16x16x32_bf16(pf[1][c2], onesf, o[1][8], 0, 0, 0);
    }
  };

  const int nc = 2 * t + 2;   // causal: kv up to 128t+127, Tk=64
  stage(0, 0);
  __syncthreads();

  int c = 0;
#pragma unroll 1
  for (; c < nc - 2; ++c) {
    stage(c + 1, (c & 1) ^ 1);
    chunk_body(std::false_type{}, c & 1, c * 64);
    __syncthreads();   // prefetch DMA drained; all reads of cur done
  }
  stage(c + 1, (c & 1) ^ 1);
  chunk_body(std::true_type{}, c & 1, c * 64);
  __syncthreads();
  ++c;
  chunk_body(std::true_type{}, c & 1, c * 64);
  __syncthreads();     // all waves done reading Ks/VTs before repack overwrite

  unsigned short (*Ob)[136] = (unsigned short (*)[136])smem;  // 34.8 KB < 64 KB
#pragma unroll
  for (int mh = 0; mh < 2; ++mh)
#pragma unroll
    for (int r = 0; r < 4; ++r) {
      const float inv = 1.0f / o[mh][8][r];   // l (same value in every lane)
#pragma unroll
      for (int di = 0; di < 8; ++di)
        Ob[wq + mh * 16 + q * 4 + r][di * 16 + l] = f2b(o[mh][di][r] * inv);
    }
  __syncthreads();
  {
    const int row = tid >> 1, g = (tid & 1) * 64;
    const int s = t * 128 + row;
    unsigned short* dst = attn + ((long)(b * SEQ + s)) * (NH * HD) + h * HD + g;
#pragma unroll
    for (int j = 0; j < 8; ++j)
      *(short8*)(dst + j * 8) = *(const short8*)&Ob[row][g + j * 8];
  }
}

// ---------------------------------------------------------------------------
extern "C" void kernel_launch(void* const* d_in, const int* in_sizes, int n_in,
                              void* d_out, int out_size, void* d_ws, size_t ws_size,
                              hipStream_t stream) {
  const float* x       = (const float*)d_in[0];   // [2,2048,2048]
  const float* w_qkv   = (const float*)d_in[1];   // [2048,3072]
  const float* w_dense = (const float*)d_in[2];   // [2048,2048]
  float* out = (float*)d_out;                     // [2,2048,2048] fp32

  char* ws = (char*)d_ws;
  const size_t MB = 1024 * 1024;
  unsigned short* xb    = (unsigned short*)(ws);            // 16 MB (aliased as attn later)
  unsigned short* wqkvT = (unsigned short*)(ws + 16 * MB);  // 12 MB
  unsigned short* wdT   = (unsigned short*)(ws + 28 * MB);  //  8 MB
  unsigned short* Qb    = (unsigned short*)(ws + 36 * MB);  // 16 MB
  unsigned short* Kb    = (unsigned short*)(ws + 52 * MB);  //  4 MB
  unsigned short* VTb   = (unsigned short*)(ws + 56 * MB);  //  4 MB
  float*          rtab  = (float*)(ws + 60 * MB);           //  1 MB  (total 61 MB)
  unsigned short* attn  = xb;   // x no longer needed after qkv GEMM

  const float qscale = 0.08838834764831845f * 1.4426950408889634f; // 1/sqrt(128)*log2e

  prep<<<PREP_TOTAL, 256, 0, stream>>>(x, xb, w_qkv, wqkvT, w_dense, wdT, rtab);

  // QKV GEMM with fused table-RoPE in the Q/K epilogue (BN=128, 768 blocks, 3/CU)
  gemm_bt<0><<<dim3(NQKV / 128, MROWS / BM), 256, 0, stream>>>(
      xb, wqkvT, MROWS, NQKV, EMB, nullptr, Qb, Kb, VTb, rtab, qscale);

  attn_kernel<<<dim3(16, NH, NBATCH), 256, 0, stream>>>(Qb, Kb, VTb, attn);

  // dense GEMM (BN=64, 1024 blocks, 4/CU)
  gemm_bt<1><<<dim3(EMB / 64, MROWS / BM), 256, 0, stream>>>(
      attn, wdT, MROWS, EMB, NH * HD, out, nullptr, nullptr, nullptr, nullptr, 0.0f);
}